// Round 2
// baseline (354.488 us; speedup 1.0000x reference)
//
#include <hip/hip_runtime.h>
#include <cstdint>
#include <cstddef>

typedef __bf16 bf16_t;
typedef __bf16 bf16x8 __attribute__((ext_vector_type(8)));
typedef __bf16 bf16x4 __attribute__((ext_vector_type(4)));
typedef float floatx4 __attribute__((ext_vector_type(4)));

#define MFMA_BF16_16x16x32(a, b, c) \
  __builtin_amdgcn_mfma_f32_16x16x32_bf16((a), (b), (c), 0, 0, 0)

static constexpr int kT = 2048;   // sequence length
static constexpr int kDM = 1024;  // d_model
static constexpr int kNH = 16;
static constexpr int kDH = 64;
static constexpr float kLog2e = 1.4426950408889634f;

// ---------------------------------------------------------------------------
// Input dtype probe: view first 8192 elements of x as bf16. For true bf16
// N(0,1) data every exponent is near 127; for fp32 data the low half of each
// float has a pseudo-random exponent field (~42% wild). flag=1 -> bf16.
// ---------------------------------------------------------------------------
__global__ __launch_bounds__(256) void detect_dtype(
    const unsigned short* __restrict__ xv, int* __restrict__ flagp) {
  __shared__ int bad_s[256];
  int bad = 0;
  for (int i = threadIdx.x; i < 8192; i += 256) {
    const unsigned e = (xv[i] >> 7) & 0xFF;
    if (e == 0xFF || (e != 0 && (e < 107 || e > 147))) bad++;
  }
  bad_s[threadIdx.x] = bad;
  __syncthreads();
  for (int s = 128; s > 0; s >>= 1) {
    if (threadIdx.x < s) bad_s[threadIdx.x] += bad_s[threadIdx.x + s];
    __syncthreads();
  }
  if (threadIdx.x == 0) *flagp = (bad_s[0] * 10 < 8192) ? 1 : 0;
}

// ---------------------------------------------------------------------------
// x -> bf16 contiguous copy (from bf16 or fp32 source per flag).
// ---------------------------------------------------------------------------
__global__ __launch_bounds__(256) void convert_x(
    const void* __restrict__ src, bf16_t* __restrict__ dst,
    const int* __restrict__ flagp, int n) {
  const int f = *flagp;
  const int i = (blockIdx.x * 256 + threadIdx.x) * 8;
  if (i >= n) return;
  if (f) {
    *(bf16x8*)(dst + i) = *(const bf16x8*)((const bf16_t*)src + i);
  } else {
    const float* s = (const float*)src + i;
    bf16x8 v;
#pragma unroll
    for (int j = 0; j < 8; j++) v[j] = (bf16_t)s[j];
    *(bf16x8*)(dst + i) = v;
  }
}

// ---------------------------------------------------------------------------
// Weight convert+transpose: W [k][n] (bf16 or fp32) -> W^T [n][k] bf16.
// 4 matrices via blockIdx.z.
// ---------------------------------------------------------------------------
__global__ __launch_bounds__(256) void convert_transpose_w(
    const void* __restrict__ w0, const void* __restrict__ w1,
    const void* __restrict__ w2, const void* __restrict__ w3,
    bf16_t* __restrict__ out_base, const int* __restrict__ flagp) {
  const int f = *flagp;
  const void* src = (blockIdx.z == 0) ? w0
                  : (blockIdx.z == 1) ? w1
                  : (blockIdx.z == 2) ? w2 : w3;
  bf16_t* dst = out_base + (size_t)blockIdx.z * (kDM * kDM);
  __shared__ bf16_t tile[64][65];  // +1 pad breaks bank alignment
  const int tx = threadIdx.x & 63;
  const int ty = threadIdx.x >> 6;  // 0..3
  const int x0 = blockIdx.x * 64;
  const int y0 = blockIdx.y * 64;
#pragma unroll
  for (int r = 0; r < 64; r += 4) {
    const size_t idx = (size_t)(y0 + ty + r) * kDM + x0 + tx;
    tile[ty + r][tx] =
        f ? ((const bf16_t*)src)[idx] : (bf16_t)((const float*)src)[idx];
  }
  __syncthreads();
#pragma unroll
  for (int r = 0; r < 64; r += 4)
    dst[(size_t)(x0 + ty + r) * kDM + y0 + tx] = tile[tx][ty + r];
}

// ---------------------------------------------------------------------------
// 128x128 GEMM core, B^T form. A points at tile's first row (A[m0..][0..K]),
// Bt points at tile's first n-row (Bt[n0..][0..K]). 256 threads = 4 waves in
// 2x2; each wave computes a 64x64 tile as 4x4 mfma_f32_16x16x32_bf16 frags.
// LDS layout [row][k] with k contiguous (32 bf16 per row) — m97 structure.
// ---------------------------------------------------------------------------
__device__ __forceinline__ void gemm_core_128x128(
    const bf16_t* __restrict__ A, const bf16_t* __restrict__ Bt, int K,
    bf16_t* __restrict__ sA, bf16_t* __restrict__ sB, floatx4 acc[4][4]) {
  const int tid = threadIdx.x;
  const int lane = tid & 63;
  const int w = tid >> 6;
  const int quad = lane >> 4;
  const int l16 = lane & 15;
  const int wm = w >> 1;
  const int wn = w & 1;
  const int sr = tid >> 2;       // staging row 0..63 (round 2 adds +64)
  const int sc = (tid & 3) * 8;  // staging col {0,8,16,24}

  for (int kk = 0; kk < K; kk += 32) {
    const bf16x8 a0 = *(const bf16x8*)(A + (size_t)sr * K + kk + sc);
    const bf16x8 a1 = *(const bf16x8*)(A + (size_t)(sr + 64) * K + kk + sc);
    const bf16x8 b0 = *(const bf16x8*)(Bt + (size_t)sr * K + kk + sc);
    const bf16x8 b1 = *(const bf16x8*)(Bt + (size_t)(sr + 64) * K + kk + sc);
    __syncthreads();  // previous iteration's readers done
    *(bf16x8*)(sA + sr * 32 + sc) = a0;
    *(bf16x8*)(sA + (sr + 64) * 32 + sc) = a1;
    *(bf16x8*)(sB + sr * 32 + sc) = b0;
    *(bf16x8*)(sB + (sr + 64) * 32 + sc) = b1;
    __syncthreads();
    bf16x8 af[4], bf[4];
#pragma unroll
    for (int mi = 0; mi < 4; mi++)
      af[mi] = *(const bf16x8*)(sA + (wm * 64 + mi * 16 + l16) * 32 + quad * 8);
#pragma unroll
    for (int ni = 0; ni < 4; ni++)
      bf[ni] = *(const bf16x8*)(sB + (wn * 64 + ni * 16 + l16) * 32 + quad * 8);
#pragma unroll
    for (int mi = 0; mi < 4; mi++)
#pragma unroll
      for (int ni = 0; ni < 4; ni++)
        acc[mi][ni] = MFMA_BF16_16x16x32(af[mi], bf[ni], acc[mi][ni]);
  }
}

// ---------------------------------------------------------------------------
// QKV projection: xb [4096][1024] @ Wt[which] -> Q/K as [B][H][T][D],
// V transposed as [B][H][D][T] (so PV B-operand reads are contiguous in t).
// grid = (N/128=8, M/128=32, 3)
// ---------------------------------------------------------------------------
__global__ __launch_bounds__(256) void qkv_proj(
    const bf16_t* __restrict__ x, const bf16_t* __restrict__ wt_base,
    bf16_t* __restrict__ Qo, bf16_t* __restrict__ Ko, bf16_t* __restrict__ Vo) {
  __shared__ bf16_t smem[2 * 128 * 32];
  const int n0 = blockIdx.x * 128;
  const int m0 = blockIdx.y * 128;
  const int which = blockIdx.z;
  const bf16_t* Bt = wt_base + (size_t)which * (kDM * kDM);

  floatx4 acc[4][4];
  const floatx4 zero4 = {0.f, 0.f, 0.f, 0.f};
#pragma unroll
  for (int mi = 0; mi < 4; mi++)
#pragma unroll
    for (int ni = 0; ni < 4; ni++) acc[mi][ni] = zero4;

  gemm_core_128x128(x + (size_t)m0 * kDM, Bt + (size_t)n0 * kDM, kDM,
                    smem, smem + 128 * 32, acc);

  const int tid = threadIdx.x;
  const int lane = tid & 63, w = tid >> 6;
  const int quad = lane >> 4, l16 = lane & 15;
  const int wm = w >> 1, wn = w & 1;

  if (which < 2) {
    bf16_t* O = (which == 0) ? Qo : Ko;
#pragma unroll
    for (int mi = 0; mi < 4; mi++) {
#pragma unroll
      for (int ni = 0; ni < 4; ni++) {
        const int n = n0 + wn * 64 + ni * 16 + l16;
        const int h = n >> 6, d = n & 63;
#pragma unroll
        for (int reg = 0; reg < 4; reg++) {
          const int m = m0 + wm * 64 + mi * 16 + quad * 4 + reg;
          const int b = m >> 11, t = m & (kT - 1);
          O[((size_t)(b * kNH + h) * kT + t) * kDH + d] = (bf16_t)acc[mi][ni][reg];
        }
      }
    }
  } else {
#pragma unroll
    for (int mi = 0; mi < 4; mi++) {
#pragma unroll
      for (int ni = 0; ni < 4; ni++) {
        const int n = n0 + wn * 64 + ni * 16 + l16;
        const int h = n >> 6, d = n & 63;
        const int m = m0 + wm * 64 + mi * 16 + quad * 4;  // reg 0 row
        const int b = m >> 11, t = m & (kT - 1);
        bf16x4 v;
        v[0] = (bf16_t)acc[mi][ni][0];
        v[1] = (bf16_t)acc[mi][ni][1];
        v[2] = (bf16_t)acc[mi][ni][2];
        v[3] = (bf16_t)acc[mi][ni][3];
        // t is a multiple of 4 -> 8B-aligned packed store of 4 consecutive t
        *(bf16x4*)(Vo + ((size_t)(b * kNH + h) * kDH + d) * kT + t) = v;
      }
    }
  }
}

// ---------------------------------------------------------------------------
// Flash attention (causal). grid = (T/128=16, B*H=32), 256 threads.
// Wave w owns q-rows [w*32, w*32+32) of the 128-row q-tile -> online-softmax
// state is wave-local; no cross-wave reduction. P round-trips through LDS
// (C-layout -> A-layout transform), padded stride 136 to break conflicts.
// ---------------------------------------------------------------------------
__global__ __launch_bounds__(256) void attn_fused(
    const bf16_t* __restrict__ Q, const bf16_t* __restrict__ K,
    const bf16_t* __restrict__ VT, bf16_t* __restrict__ Z) {
  constexpr int PS = 136;
  __shared__ bf16_t Ps[128 * PS];
  const int qi = blockIdx.x;
  const int bh = blockIdx.y;
  const int q0 = qi * 128;
  const int tid = threadIdx.x;
  const int lane = tid & 63;
  const int w = tid >> 6;
  const int quad = lane >> 4;
  const int l16 = lane & 15;
  const bf16_t* Qb = Q + (size_t)bh * kT * kDH;
  const bf16_t* Kb = K + (size_t)bh * kT * kDH;
  const bf16_t* Vb = VT + (size_t)bh * kDH * kT;

  // Q A-fragments for this wave's 32 rows (kh = which 32-wide k half of D=64)
  bf16x8 qf[2][2];
#pragma unroll
  for (int mi = 0; mi < 2; mi++)
#pragma unroll
    for (int kh = 0; kh < 2; kh++)
      qf[mi][kh] = *(const bf16x8*)(Qb + (q0 + w * 32 + mi * 16 + l16) * kDH +
                                    kh * 32 + quad * 8);

  const floatx4 zero4 = {0.f, 0.f, 0.f, 0.f};
  floatx4 of[2][4];  // O accum: [mi][d-block]
  float mrow[2][4], lrow[2][4];
#pragma unroll
  for (int mi = 0; mi < 2; mi++) {
#pragma unroll
    for (int nd = 0; nd < 4; nd++) of[mi][nd] = zero4;
#pragma unroll
    for (int r = 0; r < 4; r++) { mrow[mi][r] = -1e30f; lrow[mi][r] = 0.f; }
  }

  for (int kt = 0; kt <= qi; kt++) {
    const int kbase = kt * 128;
    // ---- S = Q K^T for 32 q-rows x 128 k-cols ----
    floatx4 sf[2][8];
#pragma unroll
    for (int mi = 0; mi < 2; mi++)
#pragma unroll
      for (int ni = 0; ni < 8; ni++) sf[mi][ni] = zero4;
#pragma unroll
    for (int kh = 0; kh < 2; kh++) {
#pragma unroll
      for (int ni = 0; ni < 8; ni++) {
        const bf16x8 kf = *(const bf16x8*)(Kb + (kbase + ni * 16 + l16) * kDH +
                                           kh * 32 + quad * 8);
        sf[0][ni] = MFMA_BF16_16x16x32(qf[0][kh], kf, sf[0][ni]);
        sf[1][ni] = MFMA_BF16_16x16x32(qf[1][kh], kf, sf[1][ni]);
      }
    }
    // ---- online softmax (per (mi,reg) = one q-row, spread over 16 lanes) ----
    const bool diag = (kt == qi);
#pragma unroll
    for (int mi = 0; mi < 2; mi++) {
#pragma unroll
      for (int reg = 0; reg < 4; reg++) {
        const int row_l = w * 32 + mi * 16 + quad * 4 + reg;  // local q row
        float sv[8];
        float vmax = -1e30f;
#pragma unroll
        for (int ni = 0; ni < 8; ni++) {
          float s = sf[mi][ni][reg] * 0.125f;  // 1/sqrt(64)
          if (diag && (ni * 16 + l16 > row_l)) s = -1e30f;
          sv[ni] = s;
          vmax = fmaxf(vmax, s);
        }
#pragma unroll
        for (int off = 1; off < 16; off <<= 1)
          vmax = fmaxf(vmax, __shfl_xor(vmax, off, 64));
        const float mprev = mrow[mi][reg];
        const float mnew = fmaxf(mprev, vmax);
        const float alpha = exp2f((mprev - mnew) * kLog2e);
        float rsum = 0.f;
#pragma unroll
        for (int ni = 0; ni < 8; ni++) {
          const float p = exp2f((sv[ni] - mnew) * kLog2e);
          rsum += p;
          Ps[row_l * PS + ni * 16 + l16] = (bf16_t)p;
        }
#pragma unroll
        for (int off = 1; off < 16; off <<= 1)
          rsum += __shfl_xor(rsum, off, 64);
        lrow[mi][reg] = lrow[mi][reg] * alpha + rsum;
        mrow[mi][reg] = mnew;
#pragma unroll
        for (int nd = 0; nd < 4; nd++) of[mi][nd][reg] *= alpha;
      }
    }
    __syncthreads();  // P writes visible before LDS A-frag reads
    // ---- O += P V  (A = P from LDS, B = V^T rows, contiguous in t) ----
#pragma unroll
    for (int ks = 0; ks < 4; ks++) {
      bf16x8 af[2];
      af[0] = *(const bf16x8*)(Ps + (w * 32 + l16) * PS + ks * 32 + quad * 8);
      af[1] = *(const bf16x8*)(Ps + (w * 32 + 16 + l16) * PS + ks * 32 + quad * 8);
#pragma unroll
      for (int nd = 0; nd < 4; nd++) {
        const bf16x8 vf = *(const bf16x8*)(Vb + (nd * 16 + l16) * kT + kbase +
                                           ks * 32 + quad * 8);
        of[0][nd] = MFMA_BF16_16x16x32(af[0], vf, of[0][nd]);
        of[1][nd] = MFMA_BF16_16x16x32(af[1], vf, of[1][nd]);
      }
    }
  }

  // ---- epilogue: Z[b][t][h*64+d] = O / l ----
  const int b = bh >> 4, h = bh & 15;
#pragma unroll
  for (int mi = 0; mi < 2; mi++) {
#pragma unroll
    for (int reg = 0; reg < 4; reg++) {
      const int t = q0 + w * 32 + mi * 16 + quad * 4 + reg;
      const float inv = 1.f / lrow[mi][reg];
#pragma unroll
      for (int nd = 0; nd < 4; nd++) {
        const int col = h * 64 + nd * 16 + l16;
        Z[(size_t)(b * kT + t) * kDM + col] = (bf16_t)(of[mi][nd][reg] * inv);
      }
    }
  }
}

// ---------------------------------------------------------------------------
// Output projection: Z [4096][1024] @ Wout^T -> out [4096][1024].
// Output dtype follows the detected input dtype (uniform-dtype problem).
// ---------------------------------------------------------------------------
__global__ __launch_bounds__(256) void out_proj(
    const bf16_t* __restrict__ Zin, const bf16_t* __restrict__ WtO,
    void* __restrict__ out, const int* __restrict__ flagp) {
  __shared__ bf16_t smem[2 * 128 * 32];
  const int f = *flagp;
  const int n0 = blockIdx.x * 128;
  const int m0 = blockIdx.y * 128;
  floatx4 acc[4][4];
  const floatx4 zero4 = {0.f, 0.f, 0.f, 0.f};
#pragma unroll
  for (int mi = 0; mi < 4; mi++)
#pragma unroll
    for (int ni = 0; ni < 4; ni++) acc[mi][ni] = zero4;

  gemm_core_128x128(Zin + (size_t)m0 * kDM, WtO + (size_t)n0 * kDM, kDM,
                    smem, smem + 128 * 32, acc);

  const int tid = threadIdx.x;
  const int lane = tid & 63, w = tid >> 6;
  const int quad = lane >> 4, l16 = lane & 15;
  const int wm = w >> 1, wn = w & 1;
#pragma unroll
  for (int mi = 0; mi < 4; mi++) {
#pragma unroll
    for (int ni = 0; ni < 4; ni++) {
      const int n = n0 + wn * 64 + ni * 16 + l16;
#pragma unroll
      for (int reg = 0; reg < 4; reg++) {
        const int m = m0 + wm * 64 + mi * 16 + quad * 4 + reg;
        if (f) {
          ((bf16_t*)out)[(size_t)m * kDM + n] = (bf16_t)acc[mi][ni][reg];
        } else {
          ((float*)out)[(size_t)m * kDM + n] = acc[mi][ni][reg];
        }
      }
    }
  }
}

// ---------------------------------------------------------------------------
// Workspace layout (bf16 elements):
//   [0,4M)   : W^T q,k,v,o   (4 x 1M)
//   [4M,8M)  : xb (x as bf16)
//   [8M,12M) : Q  [B][H][T][D]
//   [12M,16M): K  [B][H][T][D]
//   [16M,20M): V^T[B][H][D][T]
//   [20M,24M): Z  [B][T][H*D]
//   [24M]    : dtype flag (int, byte offset 48 MB)
// Total 48 MB + 4 B.
// ---------------------------------------------------------------------------
extern "C" void kernel_launch(void* const* d_in, const int* in_sizes, int n_in,
                              void* d_out, int out_size, void* d_ws,
                              size_t ws_size, hipStream_t stream) {
  const void* x = d_in[0];
  const void* Wq = d_in[1];
  const void* Wk = d_in[2];
  const void* Wv = d_in[3];
  const void* Wo = d_in[4];
  bf16_t* ws = (bf16_t*)d_ws;
  const size_t MEG = 1024 * 1024;
  bf16_t* wt = ws;                 // 4 transposed weights, 1M each
  bf16_t* xb = ws + 4 * MEG;
  bf16_t* Q = ws + 8 * MEG;
  bf16_t* Kc = ws + 12 * MEG;
  bf16_t* VT = ws + 16 * MEG;
  bf16_t* Z = ws + 20 * MEG;
  int* flagp = (int*)(ws + 24 * MEG);

  detect_dtype<<<1, 256, 0, stream>>>((const unsigned short*)x, flagp);
  convert_x<<<2048, 256, 0, stream>>>(x, xb, flagp, 4 * (int)MEG);
  convert_transpose_w<<<dim3(16, 16, 4), 256, 0, stream>>>(Wq, Wk, Wv, Wo, wt,
                                                           flagp);
  qkv_proj<<<dim3(8, 32, 3), 256, 0, stream>>>(xb, wt, Q, Kc, VT);
  attn_fused<<<dim3(16, 32), 256, 0, stream>>>(Q, Kc, VT, Z);
  out_proj<<<dim3(8, 32), 256, 0, stream>>>(Z, wt + 3 * MEG, d_out, flagp);
}